// Round 3
// baseline (354.254 us; speedup 1.0000x reference)
//
#include <hip/hip_runtime.h>
#include <stdint.h>

// ---- problem constants ----
#define HEADS 8
#define KSZ   4
#define STRD  2
#define BB    8
#define LL    2048
#define CC    1024
#define N3    3072
#define NW    1023            // windows
#define M1    (BB*LL)         // 16384 rows of qkv GEMM
#define M2    (BB*NW*KSZ)     // 32736 rows of out GEMM
#define M2PAD 32768

typedef __bf16 bf16;
typedef __bf16 bf16x8 __attribute__((ext_vector_type(8)));
typedef float  f32x4  __attribute__((ext_vector_type(4)));
typedef unsigned int  u32;
typedef unsigned short u16;

__device__ __forceinline__ float bflo(u32 u) { return __uint_as_float(u << 16); }
__device__ __forceinline__ float bfhi(u32 u) { return __uint_as_float(u & 0xffff0000u); }
__device__ __forceinline__ u16 f2bf(float f) { bf16 b = (bf16)f; return __builtin_bit_cast(u16, b); }

#define AS3(p) ((__attribute__((address_space(3))) void*)(p))
#define AS1(p) ((const __attribute__((address_space(1))) void*)(p))

// ---------------- cast x (f32 -> bf16), vectorized ----------------
__global__ __launch_bounds__(256) void cast_x_k(const float* __restrict__ in,
                                                bf16* __restrict__ out, int n4)
{
    int i = blockIdx.x * 256 + threadIdx.x;
    int stride = gridDim.x * 256;
    for (; i < n4; i += stride) {
        float4 f = reinterpret_cast<const float4*>(in)[i];
        ushort4 u;
        u.x = f2bf(f.x); u.y = f2bf(f.y); u.z = f2bf(f.z); u.w = f2bf(f.w);
        reinterpret_cast<ushort4*>(out)[i] = u;
    }
}

// ---------------- transpose + cast: src f32 [R][Ccol] -> dst bf16 [Ccol][R] ----------------
__global__ __launch_bounds__(256) void transpose_cast_k(const float* __restrict__ src,
                                                        bf16* __restrict__ dst,
                                                        int R, int Ccol)
{
    __shared__ float t[32][33];
    int tx = threadIdx.x & 31, ty = threadIdx.x >> 5;   // 32 x 8
    int c0 = blockIdx.x * 32, r0 = blockIdx.y * 32;
#pragma unroll
    for (int yy = 0; yy < 32; yy += 8)
        t[ty + yy][tx] = src[(size_t)(r0 + ty + yy) * Ccol + c0 + tx];
    __syncthreads();
#pragma unroll
    for (int yy = 0; yy < 32; yy += 8)
        dst[(size_t)(c0 + ty + yy) * R + r0 + tx] = (bf16)t[tx][ty + yy];
}

// ---------------- bf16 GEMM, A[M][K] row-major, Bt[N][K] row-major (B transposed) ----------------
// 128x128 tile, BK=32, 4 waves (2x2), each wave 64x64 = 4x4 frags of 16x16x32 MFMA.
// HAS_BIAS=1 adds bias[col]. Output Cb bf16 row-major [M][Nn].
template <int HAS_BIAS>
__global__ __launch_bounds__(256) void gemm_k(const bf16* __restrict__ A,
                                              const bf16* __restrict__ Bt,
                                              bf16* __restrict__ Cb,
                                              const float* __restrict__ bias,
                                              int K, int Nn)
{
    __shared__ __attribute__((aligned(16))) bf16 lA[128 * 32];
    __shared__ __attribute__((aligned(16))) bf16 lB[128 * 32];
    const int t = threadIdx.x;
    const int w = t >> 6, l = t & 63;
    const int wm = w >> 1, wn = w & 1;
    const int m0 = blockIdx.x * 128, n0 = blockIdx.y * 128;

    f32x4 acc[4][4] = {};

    for (int k0 = 0; k0 < K; k0 += 32) {
        // stage A and Bt tiles: 128x32 bf16 each = 8 KiB = 512 16B-chunks; 2 per thread per matrix
#pragma unroll
        for (int i = 0; i < 2; ++i) {
            int c = i * 256 + w * 64 + l;          // chunk id, lane-linear within wave
            int row = c >> 2, kc = c & 3;
            const bf16* ga = A  + (size_t)(m0 + row) * K + k0 + kc * 8;
            const bf16* gb = Bt + (size_t)(n0 + row) * K + k0 + kc * 8;
            __builtin_amdgcn_global_load_lds(AS1(ga), AS3(lA + (i * 256 + w * 64) * 8), 16, 0, 0);
            __builtin_amdgcn_global_load_lds(AS1(gb), AS3(lB + (i * 256 + w * 64) * 8), 16, 0, 0);
        }
        __syncthreads();

        bf16x8 af[4], bfr[4];
#pragma unroll
        for (int i = 0; i < 4; ++i)
            af[i] = *reinterpret_cast<const bf16x8*>(&lA[(wm * 64 + i * 16 + (l & 15)) * 32 + (l >> 4) * 8]);
#pragma unroll
        for (int j = 0; j < 4; ++j)
            bfr[j] = *reinterpret_cast<const bf16x8*>(&lB[(wn * 64 + j * 16 + (l & 15)) * 32 + (l >> 4) * 8]);
#pragma unroll
        for (int i = 0; i < 4; ++i)
#pragma unroll
            for (int j = 0; j < 4; ++j)
                acc[i][j] = __builtin_amdgcn_mfma_f32_16x16x32_bf16(af[i], bfr[j], acc[i][j], 0, 0, 0);
        __syncthreads();
    }

    // epilogue: D[row=(l>>4)*4+r][col=l&15] (m89-verified layout)
#pragma unroll
    for (int i = 0; i < 4; ++i) {
#pragma unroll
        for (int j = 0; j < 4; ++j) {
            int col = n0 + wn * 64 + j * 16 + (l & 15);
            float bv = 0.f;
            if (HAS_BIAS) bv = bias[col];
#pragma unroll
            for (int r = 0; r < 4; ++r) {
                int row = m0 + wm * 64 + i * 16 + (l >> 4) * 4 + r;
                Cb[(size_t)row * Nn + col] = (bf16)(acc[i][j][r] + bv);
            }
        }
    }
}

// ---------------- windowed attention: 1 wave per (b, n, h) ----------------
// qkv bf16 [B*L][3072]; ob bf16 [(b*NW+n)*4+q][1024]
__global__ __launch_bounds__(64) void attn_k(const bf16* __restrict__ qkv,
                                             bf16* __restrict__ ob)
{
    int bid = blockIdx.x;
    int h = bid & 7;
    int tmp = bid >> 3;
    int n = tmp % NW;
    int b = tmp / NW;
    int l = threadIdx.x;
    const size_t rowbase = ((size_t)b * LL + 2 * n) * N3;
    const int coff = h * 128 + 2 * l;    // this lane's 2 d-elements

    float q[KSZ][2], k[KSZ][2], v[KSZ][2];
#pragma unroll
    for (int i = 0; i < KSZ; ++i) {
        const bf16* rp = qkv + rowbase + (size_t)i * N3;
        u32 uq = *reinterpret_cast<const u32*>(rp + coff);
        u32 uk = *reinterpret_cast<const u32*>(rp + 1024 + coff);
        u32 uv = *reinterpret_cast<const u32*>(rp + 2048 + coff);
        q[i][0] = bflo(uq); q[i][1] = bfhi(uq);
        k[i][0] = bflo(uk); k[i][1] = bfhi(uk);
        v[i][0] = bflo(uv); v[i][1] = bfhi(uv);
    }

    float dots[KSZ][KSZ];
#pragma unroll
    for (int i = 0; i < KSZ; ++i)
#pragma unroll
        for (int j = 0; j < KSZ; ++j) {
            float p = q[i][0] * k[j][0] + q[i][1] * k[j][1];
#pragma unroll
            for (int off = 32; off >= 1; off >>= 1)
                p += __shfl_xor(p, off);
            dots[i][j] = p * 0.03125f;   // * C^-0.5
        }

#pragma unroll
    for (int i = 0; i < KSZ; ++i) {
        float m = fmaxf(fmaxf(dots[i][0], dots[i][1]), fmaxf(dots[i][2], dots[i][3]));
        float e[KSZ], s = 0.f;
#pragma unroll
        for (int j = 0; j < KSZ; ++j) { e[j] = __expf(dots[i][j] - m); s += e[j]; }
        float inv = 1.f / s;
        float o0 = 0.f, o1 = 0.f;
#pragma unroll
        for (int j = 0; j < KSZ; ++j) {
            float a = e[j] * inv;
            o0 += a * v[j][0];
            o1 += a * v[j][1];
        }
        size_t orow = (size_t)(b * NW + n) * KSZ + i;
        u32 pk = (u32)f2bf(o0) | ((u32)f2bf(o1) << 16);
        *reinterpret_cast<u32*>(ob + orow * CC + coff) = pk;
    }
}

// ---------------- gather: out[b][l][:] = sum of 1-2 contributing y rows ----------------
__global__ __launch_bounds__(256) void gather_k(const bf16* __restrict__ yb,
                                                float* __restrict__ out)
{
    size_t i = (size_t)blockIdx.x * 256 + threadIdx.x;   // over B*L*C/2 pairs
    size_t e0 = i * 2;
    int col = (int)(e0 & (CC - 1));
    size_t row = e0 >> 10;          // b*L + l
    int l = (int)(row & (LL - 1));
    int b = (int)(row >> 11);

    float s0 = 0.f, s1 = 0.f;
    int n1 = l >> 1, q1 = l & 1;
    if (n1 <= NW - 1) {
        size_t r = (size_t)(b * NW + n1) * KSZ + q1;
        u32 u = *reinterpret_cast<const u32*>(yb + r * CC + col);
        s0 += bflo(u); s1 += bfhi(u);
    }
    int n0v = n1 - 1, q0 = (l & 1) + 2;
    if (n0v >= 0) {
        size_t r = (size_t)(b * NW + n0v) * KSZ + q0;
        u32 u = *reinterpret_cast<const u32*>(yb + r * CC + col);
        s0 += bflo(u); s1 += bfhi(u);
    }
    float2 o; o.x = s0; o.y = s1;
    *reinterpret_cast<float2*>(out + e0) = o;
}

// ---------------- launch ----------------
extern "C" void kernel_launch(void* const* d_in, const int* in_sizes, int n_in,
                              void* d_out, int out_size, void* d_ws, size_t ws_size,
                              hipStream_t stream)
{
    const float* x     = (const float*)d_in[0];
    const float* w_qkv = (const float*)d_in[1];
    const float* w_out = (const float*)d_in[2];
    const float* b_out = (const float*)d_in[3];
    float* out = (float*)d_out;
    char* ws = (char*)d_ws;

    // ws layout (bytes):
    bf16* xb    = (bf16*)(ws);                  // 16384*1024*2  = 33,554,432
    bf16* wqkvT = (bf16*)(ws + 33554432);       //  3072*1024*2  =  6,291,456
    bf16* woutT = (bf16*)(ws + 39845888);       //  1024*1024*2  =  2,097,152
    bf16* qkvb  = (bf16*)(ws + 41943040);       // 16384*3072*2  = 100,663,296
    bf16* yb    = (bf16*)(ws + 41943040);       // aliases qkvb (dead after attn): 32768*1024*2
    bf16* ob    = (bf16*)(ws + 142606336);      // 32768*1024*2  = 67,108,864  (rows padded to 32768)
    // total: 209,715,200 bytes

    cast_x_k<<<2048, 256, 0, stream>>>(x, xb, M1 * CC / 4);
    transpose_cast_k<<<dim3(N3 / 32, CC / 32), 256, 0, stream>>>(w_qkv, wqkvT, CC, N3);
    transpose_cast_k<<<dim3(CC / 32, CC / 32), 256, 0, stream>>>(w_out, woutT, CC, CC);

    gemm_k<0><<<dim3(M1 / 128, N3 / 128), 256, 0, stream>>>(xb, wqkvT, qkvb, nullptr, CC, N3);

    attn_k<<<BB * NW * HEADS, 64, 0, stream>>>(qkvb, ob);

    gemm_k<1><<<dim3(M2PAD / 128, CC / 128), 256, 0, stream>>>(ob, woutT, yb, b_out, CC, CC);

    gather_k<<<(BB * LL * CC / 2) / 256, 256, 0, stream>>>(yb, out);
}

// Round 4
// 290.492 us; speedup vs baseline: 1.2195x; 1.2195x over previous
//
#include <hip/hip_runtime.h>
#include <stdint.h>

// ---- problem constants ----
#define HEADS 8
#define KSZ   4
#define STRD  2
#define BB    8
#define LL    2048
#define CC    1024
#define N3    3072
#define NW    1023            // windows
#define M1    (BB*LL)         // 16384 rows of qkv GEMM
#define M2    (BB*NW*KSZ)     // 32736 rows of out GEMM
#define M2PAD 32768

typedef __bf16 bf16;
typedef __bf16 bf16x8 __attribute__((ext_vector_type(8)));
typedef float  f32x4  __attribute__((ext_vector_type(4)));
typedef unsigned int  u32;
typedef unsigned short u16;

__device__ __forceinline__ float bflo(u32 u) { return __uint_as_float(u << 16); }
__device__ __forceinline__ float bfhi(u32 u) { return __uint_as_float(u & 0xffff0000u); }
__device__ __forceinline__ u16 f2bf(float f) { bf16 b = (bf16)f; return __builtin_bit_cast(u16, b); }

#define AS3(p) ((__attribute__((address_space(3))) void*)(p))
#define AS1(p) ((const __attribute__((address_space(1))) void*)(p))

// ---------------- cast x (f32 -> bf16), vectorized ----------------
__global__ __launch_bounds__(256) void cast_x_k(const float* __restrict__ in,
                                                bf16* __restrict__ out, int n4)
{
    int i = blockIdx.x * 256 + threadIdx.x;
    int stride = gridDim.x * 256;
    for (; i < n4; i += stride) {
        float4 f = reinterpret_cast<const float4*>(in)[i];
        ushort4 u;
        u.x = f2bf(f.x); u.y = f2bf(f.y); u.z = f2bf(f.z); u.w = f2bf(f.w);
        reinterpret_cast<ushort4*>(out)[i] = u;
    }
}

// ---------------- transpose + cast: src f32 [R][Ccol] -> dst bf16 [Ccol][R] ----------------
__global__ __launch_bounds__(256) void transpose_cast_k(const float* __restrict__ src,
                                                        bf16* __restrict__ dst,
                                                        int R, int Ccol)
{
    __shared__ float t[32][33];
    int tx = threadIdx.x & 31, ty = threadIdx.x >> 5;   // 32 x 8
    int c0 = blockIdx.x * 32, r0 = blockIdx.y * 32;
#pragma unroll
    for (int yy = 0; yy < 32; yy += 8)
        t[ty + yy][tx] = src[(size_t)(r0 + ty + yy) * Ccol + c0 + tx];
    __syncthreads();
#pragma unroll
    for (int yy = 0; yy < 32; yy += 8)
        dst[(size_t)(c0 + ty + yy) * R + r0 + tx] = (bf16)t[tx][ty + yy];
}

// ---------------- 256x256 8-phase bf16 GEMM (T2+T3+T4+T5) ----------------
// A[M][K] row-major, Bt[N][K] row-major. 8 waves (2M x 4N), per-wave 128x64.
// BK=64; per K-tile 4 phases of 16 MFMA (quadrants). Double-buffered LDS,
// XOR-swizzled (byte ^= (row&7)<<4) via pre-swizzled global source (linear
// gload_lds dest). Stage A(j+2) at P3, B(j+2) at P4 (regions retired at P2/P3
// trailing barriers). vmcnt(8) counted at P4 only; vmcnt(0) once at j=NT-2.
__device__ __forceinline__ void stage8(const bf16* __restrict__ G, bf16* dst,
                                       int baserow, int kt, int K,
                                       int wid, int l, int kch)
{
#pragma unroll
    for (int qd = 0; qd < 4; ++qd) {
        int row = ((wid * 4 + qd) << 3) + (l >> 3);
        const bf16* src = G + (size_t)(baserow + row) * K + kt * 64 + kch;
        __builtin_amdgcn_global_load_lds(AS1(src), AS3(dst + (wid * 4 + qd) * 512), 16, 0, 0);
    }
}

template <int HAS_BIAS>
__global__ __launch_bounds__(512, 1) void gemm8_k(const bf16* __restrict__ A,
                                                  const bf16* __restrict__ Bt,
                                                  bf16* __restrict__ Cb,
                                                  const float* __restrict__ bias,
                                                  int K, int Nn)
{
    __shared__ __attribute__((aligned(16))) bf16 sA[2][256 * 64];
    __shared__ __attribute__((aligned(16))) bf16 sB[2][256 * 64];

    const int tid = threadIdx.x;
    const int l = tid & 63, wid = tid >> 6;
    const int wm = wid >> 2, wn = wid & 3;
    const int l15 = l & 15, l4 = l >> 4;
    const int xr = (l & 7) << 4;                      // read-side byte XOR (row&7 == l&7)
    const int kch = ((l & 7) ^ ((l >> 3) & 7)) * 8;   // write-side inverse-swizzled k offset (bf16)

    // XCD-aware block swizzle (grid % 8 == 0, bijective)
    const int nwg = gridDim.x;
    const int wg = ((blockIdx.x & 7) * (nwg >> 3)) + (blockIdx.x >> 3);
    const int nbn = Nn >> 8;
    const int m0 = (wg / nbn) << 8, n0 = (wg % nbn) << 8;

    const int NT = K >> 6;

    const int rA = wm * 128 + l15;    // A frag row base in tile
    const int rB = wn * 64 + l15;     // B frag row base in tile
    int offK[2];                      // per-ks swizzled bf16 offset within row
#pragma unroll
    for (int ks = 0; ks < 2; ++ks)
        offK[ks] = ((ks * 64 + l4 * 16) ^ xr) >> 1;

    f32x4 acc[8][4] = {};
    bf16x8 aLo[4][2], aHi[4][2], bLo[2][2], bHi[2][2];

    // prologue: K-tile 0 -> buf0, K-tile 1 -> buf1 (16 loads/thread)
    stage8(A, sA[0], m0, 0, K, wid, l, kch);
    stage8(Bt, sB[0], n0, 0, K, wid, l, kch);
    stage8(A, sA[1], m0, 1, K, wid, l, kch);
    stage8(Bt, sB[1], n0, 1, K, wid, l, kch);
    asm volatile("s_waitcnt vmcnt(8)" ::: "memory");   // K-tile 0 landed
    __builtin_amdgcn_s_barrier();
    __builtin_amdgcn_sched_barrier(0);

    for (int j = 0; j < NT; ++j) {
        const bf16* tA = sA[j & 1];
        const bf16* tB = sB[j & 1];
        bf16* wA = sA[j & 1];
        bf16* wB = sB[j & 1];

        // ---- P1: ds aLo(8) + bLo(4); MFMA m0-3 x n0-1 ----
#pragma unroll
        for (int m = 0; m < 4; ++m)
#pragma unroll
            for (int ks = 0; ks < 2; ++ks)
                aLo[m][ks] = *reinterpret_cast<const bf16x8*>(&tA[(rA + m * 16) * 64 + offK[ks]]);
#pragma unroll
        for (int n = 0; n < 2; ++n)
#pragma unroll
            for (int ks = 0; ks < 2; ++ks)
                bLo[n][ks] = *reinterpret_cast<const bf16x8*>(&tB[(rB + n * 16) * 64 + offK[ks]]);
        __builtin_amdgcn_s_setprio(1);
#pragma unroll
        for (int m = 0; m < 4; ++m)
#pragma unroll
            for (int n = 0; n < 2; ++n)
#pragma unroll
                for (int ks = 0; ks < 2; ++ks)
                    acc[m][n] = __builtin_amdgcn_mfma_f32_16x16x32_bf16(aLo[m][ks], bLo[n][ks], acc[m][n], 0, 0, 0);
        __builtin_amdgcn_s_setprio(0);
        __builtin_amdgcn_s_barrier();
        __builtin_amdgcn_sched_barrier(0);

        // ---- P2: ds aHi(8); MFMA m4-7 x n0-1 ----  (A region fully read after this)
#pragma unroll
        for (int m = 0; m < 4; ++m)
#pragma unroll
            for (int ks = 0; ks < 2; ++ks)
                aHi[m][ks] = *reinterpret_cast<const bf16x8*>(&tA[(rA + 64 + m * 16) * 64 + offK[ks]]);
        __builtin_amdgcn_s_setprio(1);
#pragma unroll
        for (int m = 0; m < 4; ++m)
#pragma unroll
            for (int n = 0; n < 2; ++n)
#pragma unroll
                for (int ks = 0; ks < 2; ++ks)
                    acc[4 + m][n] = __builtin_amdgcn_mfma_f32_16x16x32_bf16(aHi[m][ks], bLo[n][ks], acc[4 + m][n], 0, 0, 0);
        __builtin_amdgcn_s_setprio(0);
        __builtin_amdgcn_s_barrier();
        __builtin_amdgcn_sched_barrier(0);

        // ---- P3: ds bHi(4); stage A(j+2) into freed A region; MFMA m4-7 x n2-3 ----
#pragma unroll
        for (int n = 0; n < 2; ++n)
#pragma unroll
            for (int ks = 0; ks < 2; ++ks)
                bHi[n][ks] = *reinterpret_cast<const bf16x8*>(&tB[(rB + 32 + n * 16) * 64 + offK[ks]]);
        if (j + 2 < NT)
            stage8(A, wA, m0, j + 2, K, wid, l, kch);
        __builtin_amdgcn_s_setprio(1);
#pragma unroll
        for (int m = 0; m < 4; ++m)
#pragma unroll
            for (int n = 0; n < 2; ++n)
#pragma unroll
                for (int ks = 0; ks < 2; ++ks)
                    acc[4 + m][2 + n] = __builtin_amdgcn_mfma_f32_16x16x32_bf16(aHi[m][ks], bHi[n][ks], acc[4 + m][2 + n], 0, 0, 0);
        __builtin_amdgcn_s_setprio(0);
        __builtin_amdgcn_s_barrier();
        __builtin_amdgcn_sched_barrier(0);

        // ---- P4: stage B(j+2) into freed B region; MFMA m0-3 x n2-3; counted vmcnt ----
        if (j + 2 < NT)
            stage8(Bt, wB, n0, j + 2, K, wid, l, kch);
        __builtin_amdgcn_s_setprio(1);
#pragma unroll
        for (int m = 0; m < 4; ++m)
#pragma unroll
            for (int n = 0; n < 2; ++n)
#pragma unroll
                for (int ks = 0; ks < 2; ++ks)
                    acc[m][2 + n] = __builtin_amdgcn_mfma_f32_16x16x32_bf16(aLo[m][ks], bHi[n][ks], acc[m][2 + n], 0, 0, 0);
        __builtin_amdgcn_s_setprio(0);
        if (j < NT - 2)
            asm volatile("s_waitcnt vmcnt(8)" ::: "memory");   // K-tile j+1 landed
        else if (j == NT - 2)
            asm volatile("s_waitcnt vmcnt(0)" ::: "memory");   // drain for last tile
        __builtin_amdgcn_s_barrier();
        __builtin_amdgcn_sched_barrier(0);
    }

    // epilogue: D[row=(l>>4)*4+r][col=l&15] per frag (m89-verified layout)
#pragma unroll
    for (int m = 0; m < 8; ++m) {
        int row = m0 + wm * 128 + m * 16 + l4 * 4;
#pragma unroll
        for (int n = 0; n < 4; ++n) {
            int col = n0 + wn * 64 + n * 16 + l15;
            float bv = HAS_BIAS ? bias[col] : 0.f;
#pragma unroll
            for (int r = 0; r < 4; ++r)
                Cb[(size_t)(row + r) * Nn + col] = (bf16)(acc[m][n][r] + bv);
        }
    }
}

// ---------------- windowed attention: 1 wave per (b, n, h) ----------------
// qkv bf16 [B*L][3072]; ob bf16 [(b*NW+n)*4+q][1024]
__global__ __launch_bounds__(64) void attn_k(const bf16* __restrict__ qkv,
                                             bf16* __restrict__ ob)
{
    int bid = blockIdx.x;
    int h = bid & 7;
    int tmp = bid >> 3;
    int n = tmp % NW;
    int b = tmp / NW;
    int l = threadIdx.x;
    const size_t rowbase = ((size_t)b * LL + 2 * n) * N3;
    const int coff = h * 128 + 2 * l;    // this lane's 2 d-elements

    float q[KSZ][2], k[KSZ][2], v[KSZ][2];
#pragma unroll
    for (int i = 0; i < KSZ; ++i) {
        const bf16* rp = qkv + rowbase + (size_t)i * N3;
        u32 uq = *reinterpret_cast<const u32*>(rp + coff);
        u32 uk = *reinterpret_cast<const u32*>(rp + 1024 + coff);
        u32 uv = *reinterpret_cast<const u32*>(rp + 2048 + coff);
        q[i][0] = bflo(uq); q[i][1] = bfhi(uq);
        k[i][0] = bflo(uk); k[i][1] = bfhi(uk);
        v[i][0] = bflo(uv); v[i][1] = bfhi(uv);
    }

    float dots[KSZ][KSZ];
#pragma unroll
    for (int i = 0; i < KSZ; ++i)
#pragma unroll
        for (int j = 0; j < KSZ; ++j) {
            float p = q[i][0] * k[j][0] + q[i][1] * k[j][1];
#pragma unroll
            for (int off = 32; off >= 1; off >>= 1)
                p += __shfl_xor(p, off);
            dots[i][j] = p * 0.03125f;   // * C^-0.5
        }

#pragma unroll
    for (int i = 0; i < KSZ; ++i) {
        float m = fmaxf(fmaxf(dots[i][0], dots[i][1]), fmaxf(dots[i][2], dots[i][3]));
        float e[KSZ], s = 0.f;
#pragma unroll
        for (int j = 0; j < KSZ; ++j) { e[j] = __expf(dots[i][j] - m); s += e[j]; }
        float inv = 1.f / s;
        float o0 = 0.f, o1 = 0.f;
#pragma unroll
        for (int j = 0; j < KSZ; ++j) {
            float a = e[j] * inv;
            o0 += a * v[j][0];
            o1 += a * v[j][1];
        }
        size_t orow = (size_t)(b * NW + n) * KSZ + i;
        u32 pk = (u32)f2bf(o0) | ((u32)f2bf(o1) << 16);
        *reinterpret_cast<u32*>(ob + orow * CC + coff) = pk;
    }
}

// ---------------- gather: out[b][l][:] = sum of 1-2 contributing y rows ----------------
__global__ __launch_bounds__(256) void gather_k(const bf16* __restrict__ yb,
                                                float* __restrict__ out)
{
    size_t i = (size_t)blockIdx.x * 256 + threadIdx.x;   // over B*L*C/2 pairs
    size_t e0 = i * 2;
    int col = (int)(e0 & (CC - 1));
    size_t row = e0 >> 10;          // b*L + l
    int l = (int)(row & (LL - 1));
    int b = (int)(row >> 11);

    float s0 = 0.f, s1 = 0.f;
    int n1 = l >> 1, q1 = l & 1;
    if (n1 <= NW - 1) {
        size_t r = (size_t)(b * NW + n1) * KSZ + q1;
        u32 u = *reinterpret_cast<const u32*>(yb + r * CC + col);
        s0 += bflo(u); s1 += bfhi(u);
    }
    int n0v = n1 - 1, q0 = (l & 1) + 2;
    if (n0v >= 0) {
        size_t r = (size_t)(b * NW + n0v) * KSZ + q0;
        u32 u = *reinterpret_cast<const u32*>(yb + r * CC + col);
        s0 += bflo(u); s1 += bfhi(u);
    }
    float2 o; o.x = s0; o.y = s1;
    *reinterpret_cast<float2*>(out + e0) = o;
}

// ---------------- launch ----------------
extern "C" void kernel_launch(void* const* d_in, const int* in_sizes, int n_in,
                              void* d_out, int out_size, void* d_ws, size_t ws_size,
                              hipStream_t stream)
{
    const float* x     = (const float*)d_in[0];
    const float* w_qkv = (const float*)d_in[1];
    const float* w_out = (const float*)d_in[2];
    const float* b_out = (const float*)d_in[3];
    float* out = (float*)d_out;
    char* ws = (char*)d_ws;

    // ws layout (bytes):
    bf16* xb    = (bf16*)(ws);                  // 16384*1024*2  = 33,554,432
    bf16* wqkvT = (bf16*)(ws + 33554432);       //  3072*1024*2  =  6,291,456
    bf16* woutT = (bf16*)(ws + 39845888);       //  1024*1024*2  =  2,097,152
    bf16* qkvb  = (bf16*)(ws + 41943040);       // 16384*3072*2  = 100,663,296
    bf16* yb    = (bf16*)(ws + 41943040);       // aliases qkvb (dead after attn): 32768*1024*2
    bf16* ob    = (bf16*)(ws + 142606336);      // 32768*1024*2  = 67,108,864  (rows padded to 32768)
    // total: 209,715,200 bytes

    cast_x_k<<<2048, 256, 0, stream>>>(x, xb, M1 * CC / 4);
    transpose_cast_k<<<dim3(N3 / 32, CC / 32), 256, 0, stream>>>(w_qkv, wqkvT, CC, N3);
    transpose_cast_k<<<dim3(CC / 32, CC / 32), 256, 0, stream>>>(w_out, woutT, CC, CC);

    // GEMM1: 16384x3072x1024 -> 64*12 = 768 blocks (768 % 8 == 0)
    gemm8_k<0><<<(M1 / 256) * (N3 / 256), 512, 0, stream>>>(xb, wqkvT, qkvb, nullptr, CC, N3);

    attn_k<<<BB * NW * HEADS, 64, 0, stream>>>(qkvb, ob);

    // GEMM2: 32768x1024x1024 -> 128*4 = 512 blocks (512 % 8 == 0)
    gemm8_k<1><<<(M2PAD / 256) * (CC / 256), 512, 0, stream>>>(ob, woutT, yb, b_out, CC, CC);

    gather_k<<<(BB * LL * CC / 2) / 256, 256, 0, stream>>>(yb, out);
}

// Round 5
// 286.760 us; speedup vs baseline: 1.2354x; 1.0130x over previous
//
#include <hip/hip_runtime.h>
#include <stdint.h>

// ---- problem constants ----
#define HEADS 8
#define KSZ   4
#define STRD  2
#define BB    8
#define LL    2048
#define CC    1024
#define N3    3072
#define NW    1023            // windows
#define M1    (BB*LL)         // 16384 rows of qkv GEMM
#define M2    (BB*NW*KSZ)     // 32736 rows of out GEMM
#define M2PAD 32768
#define GK    1024            // K of both GEMMs
#define NTT   16              // K-tiles per output tile (GK/64)

typedef __bf16 bf16;
typedef __bf16 bf16x8 __attribute__((ext_vector_type(8)));
typedef float  f32x4  __attribute__((ext_vector_type(4)));
typedef unsigned int  u32;
typedef unsigned short u16;

__device__ __forceinline__ float bflo(u32 u) { return __uint_as_float(u << 16); }
__device__ __forceinline__ float bfhi(u32 u) { return __uint_as_float(u & 0xffff0000u); }
__device__ __forceinline__ u16 f2bf(float f) { bf16 b = (bf16)f; return __builtin_bit_cast(u16, b); }

#define AS3(p) ((__attribute__((address_space(3))) void*)(p))
#define AS1(p) ((const __attribute__((address_space(1))) void*)(p))

// ---------------- cast x (f32 -> bf16), vectorized ----------------
__global__ __launch_bounds__(256) void cast_x_k(const float* __restrict__ in,
                                                bf16* __restrict__ out, int n4)
{
    int i = blockIdx.x * 256 + threadIdx.x;
    int stride = gridDim.x * 256;
    for (; i < n4; i += stride) {
        float4 f = reinterpret_cast<const float4*>(in)[i];
        ushort4 u;
        u.x = f2bf(f.x); u.y = f2bf(f.y); u.z = f2bf(f.z); u.w = f2bf(f.w);
        reinterpret_cast<ushort4*>(out)[i] = u;
    }
}

// ---------------- transpose + cast: src f32 [R][Ccol] -> dst bf16 [Ccol][R] ----------------
__global__ __launch_bounds__(256) void transpose_cast_k(const float* __restrict__ src,
                                                        bf16* __restrict__ dst,
                                                        int R, int Ccol)
{
    __shared__ float t[32][33];
    int tx = threadIdx.x & 31, ty = threadIdx.x >> 5;   // 32 x 8
    int c0 = blockIdx.x * 32, r0 = blockIdx.y * 32;
#pragma unroll
    for (int yy = 0; yy < 32; yy += 8)
        t[ty + yy][tx] = src[(size_t)(r0 + ty + yy) * Ccol + c0 + tx];
    __syncthreads();
#pragma unroll
    for (int yy = 0; yy < 32; yy += 8)
        dst[(size_t)(c0 + ty + yy) * R + r0 + tx] = (bf16)t[tx][ty + yy];
}

// ---------------- persistent 256x256 8-phase bf16 GEMM (T2+T3+T4+T5) ----------------
// Each block processes T output tiles in ONE continuous K-tile pipeline of
// length JT = T*NTT. stage(j+2) runs across tile boundaries; epilogue (no LDS)
// is issued between P4-barrier and next P1, overlapping store drain with the
// next tile's compute. vmcnt ledger: stores precede stage(j+2) in issue order,
// so vmcnt(8) still implies stage(j+1) landed.
__device__ __forceinline__ void stage8(const bf16* __restrict__ G, bf16* dst,
                                       int baserow, int kt,
                                       int wid, int l, int kch)
{
#pragma unroll
    for (int qd = 0; qd < 4; ++qd) {
        int row = ((wid * 4 + qd) << 3) + (l >> 3);
        const bf16* src = G + (size_t)(baserow + row) * GK + kt * 64 + kch;
        __builtin_amdgcn_global_load_lds(AS1(src), AS3(dst + (wid * 4 + qd) * 512), 16, 0, 0);
    }
}

template <int HAS_BIAS, int T>
__global__ __launch_bounds__(512, 1) void gemm8p_k(const bf16* __restrict__ A,
                                                   const bf16* __restrict__ Bt,
                                                   bf16* __restrict__ Cb,
                                                   const float* __restrict__ bias,
                                                   int Nn)
{
    __shared__ __attribute__((aligned(16))) bf16 sA[2][256 * 64];
    __shared__ __attribute__((aligned(16))) bf16 sB[2][256 * 64];

    const int tid = threadIdx.x;
    const int l = tid & 63, wid = tid >> 6;
    const int wm = wid >> 2, wn = wid & 3;
    const int l15 = l & 15, l4 = l >> 4;
    const int xr = (l & 7) << 4;                      // read-side byte XOR (row&7 == l&7)
    const int kch = ((l & 7) ^ ((l >> 3) & 7)) * 8;   // write-side inverse-swizzled k offset

    // XCD-aware block swizzle (grid = 256, % 8 == 0, bijective)
    const int nwg = gridDim.x;
    const int wg = ((blockIdx.x & 7) * (nwg >> 3)) + (blockIdx.x >> 3);
    const int nbn = Nn >> 8;
    const int JT = T * NTT;

    int ti = wg * T;                                  // current output tile
    int m0 = (ti / nbn) << 8, n0 = (ti % nbn) << 8;

    const int rA = wm * 128 + l15;
    const int rB = wn * 64 + l15;
    int offK[2];
#pragma unroll
    for (int ks = 0; ks < 2; ++ks)
        offK[ks] = ((ks * 64 + l4 * 16) ^ xr) >> 1;

    f32x4 acc[8][4] = {};
    bf16x8 aLo[4][2], aHi[4][2], bLo[2][2], bHi[2][2];

    // prologue: K-tile 0 -> buf0, K-tile 1 -> buf1 (tile ti)
    stage8(A, sA[0], m0, 0, wid, l, kch);
    stage8(Bt, sB[0], n0, 0, wid, l, kch);
    stage8(A, sA[1], m0, 1, wid, l, kch);
    stage8(Bt, sB[1], n0, 1, wid, l, kch);
    asm volatile("s_waitcnt vmcnt(8)" ::: "memory");   // K-tile 0 landed
    __builtin_amdgcn_s_barrier();
    __builtin_amdgcn_sched_barrier(0);

    for (int j = 0; j < JT; ++j) {
        const bf16* tA = sA[j & 1];
        const bf16* tB = sB[j & 1];
        bf16* wA = sA[j & 1];
        bf16* wB = sB[j & 1];

        // next-stage coordinates (tile of j+2)
        const int jn = j + 2;
        const bool doStage = jn < JT;
        int ktn = jn & (NTT - 1), m0n = 0, n0n = 0;
        if (doStage) {
            int tin = wg * T + (jn >> 4);              // NTT == 16
            m0n = (tin / nbn) << 8;
            n0n = (tin % nbn) << 8;
        }

        // ---- P1: ds aLo(8) + bLo(4); MFMA m0-3 x n0-1 ----
#pragma unroll
        for (int m = 0; m < 4; ++m)
#pragma unroll
            for (int ks = 0; ks < 2; ++ks)
                aLo[m][ks] = *reinterpret_cast<const bf16x8*>(&tA[(rA + m * 16) * 64 + offK[ks]]);
#pragma unroll
        for (int n = 0; n < 2; ++n)
#pragma unroll
            for (int ks = 0; ks < 2; ++ks)
                bLo[n][ks] = *reinterpret_cast<const bf16x8*>(&tB[(rB + n * 16) * 64 + offK[ks]]);
        __builtin_amdgcn_s_setprio(1);
#pragma unroll
        for (int m = 0; m < 4; ++m)
#pragma unroll
            for (int n = 0; n < 2; ++n)
#pragma unroll
                for (int ks = 0; ks < 2; ++ks)
                    acc[m][n] = __builtin_amdgcn_mfma_f32_16x16x32_bf16(aLo[m][ks], bLo[n][ks], acc[m][n], 0, 0, 0);
        __builtin_amdgcn_s_setprio(0);
        __builtin_amdgcn_s_barrier();
        __builtin_amdgcn_sched_barrier(0);

        // ---- P2: ds aHi(8); MFMA m4-7 x n0-1 ----  (A region fully read after this)
#pragma unroll
        for (int m = 0; m < 4; ++m)
#pragma unroll
            for (int ks = 0; ks < 2; ++ks)
                aHi[m][ks] = *reinterpret_cast<const bf16x8*>(&tA[(rA + 64 + m * 16) * 64 + offK[ks]]);
        __builtin_amdgcn_s_setprio(1);
#pragma unroll
        for (int m = 0; m < 4; ++m)
#pragma unroll
            for (int n = 0; n < 2; ++n)
#pragma unroll
                for (int ks = 0; ks < 2; ++ks)
                    acc[4 + m][n] = __builtin_amdgcn_mfma_f32_16x16x32_bf16(aHi[m][ks], bLo[n][ks], acc[4 + m][n], 0, 0, 0);
        __builtin_amdgcn_s_setprio(0);
        __builtin_amdgcn_s_barrier();
        __builtin_amdgcn_sched_barrier(0);

        // ---- P3: ds bHi(4); stage A(j+2) into freed A region; MFMA m4-7 x n2-3 ----
#pragma unroll
        for (int n = 0; n < 2; ++n)
#pragma unroll
            for (int ks = 0; ks < 2; ++ks)
                bHi[n][ks] = *reinterpret_cast<const bf16x8*>(&tB[(rB + 32 + n * 16) * 64 + offK[ks]]);
        if (doStage)
            stage8(A, wA, m0n, ktn, wid, l, kch);
        __builtin_amdgcn_s_setprio(1);
#pragma unroll
        for (int m = 0; m < 4; ++m)
#pragma unroll
            for (int n = 0; n < 2; ++n)
#pragma unroll
                for (int ks = 0; ks < 2; ++ks)
                    acc[4 + m][2 + n] = __builtin_amdgcn_mfma_f32_16x16x32_bf16(aHi[m][ks], bHi[n][ks], acc[4 + m][2 + n], 0, 0, 0);
        __builtin_amdgcn_s_setprio(0);
        __builtin_amdgcn_s_barrier();
        __builtin_amdgcn_sched_barrier(0);

        // ---- P4: stage B(j+2) into freed B region; MFMA m0-3 x n2-3; counted vmcnt ----
        if (doStage)
            stage8(Bt, wB, n0n, ktn, wid, l, kch);
        __builtin_amdgcn_s_setprio(1);
#pragma unroll
        for (int m = 0; m < 4; ++m)
#pragma unroll
            for (int n = 0; n < 2; ++n)
#pragma unroll
                for (int ks = 0; ks < 2; ++ks)
                    acc[m][2 + n] = __builtin_amdgcn_mfma_f32_16x16x32_bf16(aLo[m][ks], bHi[n][ks], acc[m][2 + n], 0, 0, 0);
        __builtin_amdgcn_s_setprio(0);
        if (j < JT - 2)
            asm volatile("s_waitcnt vmcnt(8)" ::: "memory");   // K-tile j+1 landed
        else if (j == JT - 2)
            asm volatile("s_waitcnt vmcnt(0)" ::: "memory");   // drain for last tile
        __builtin_amdgcn_s_barrier();
        __builtin_amdgcn_sched_barrier(0);

        // ---- output-tile boundary: epilogue (no LDS access), then reset ----
        if ((j & (NTT - 1)) == NTT - 1) {
#pragma unroll
            for (int m = 0; m < 8; ++m) {
                int row = m0 + wm * 128 + m * 16 + l4 * 4;
#pragma unroll
                for (int n = 0; n < 4; ++n) {
                    int col = n0 + wn * 64 + n * 16 + l15;
                    float bv = HAS_BIAS ? bias[col] : 0.f;
#pragma unroll
                    for (int r = 0; r < 4; ++r)
                        Cb[(size_t)(row + r) * Nn + col] = (bf16)(acc[m][n][r] + bv);
                }
            }
            if (j + 1 < JT) {
#pragma unroll
                for (int m = 0; m < 8; ++m)
#pragma unroll
                    for (int n = 0; n < 4; ++n)
#pragma unroll
                        for (int r = 0; r < 4; ++r)
                            acc[m][n][r] = 0.f;
                ti += 1;
                m0 = (ti / nbn) << 8;
                n0 = (ti % nbn) << 8;
            }
        }
    }
}

// ---------------- windowed attention: 4 waves/block, 1 wave per (b, n, h) ----------------
// qkv bf16 [B*L][3072]; ob bf16 [(b*NW+n)*4+q][1024]
__global__ __launch_bounds__(256) void attn_k(const bf16* __restrict__ qkv,
                                              bf16* __restrict__ ob)
{
    int task = blockIdx.x * 4 + (threadIdx.x >> 6);
    int h = task & 7;
    int tmp = task >> 3;
    int n = tmp % NW;
    int b = tmp / NW;
    int l = threadIdx.x & 63;
    const size_t rowbase = ((size_t)b * LL + 2 * n) * N3;
    const int coff = h * 128 + 2 * l;    // this lane's 2 d-elements

    float q[KSZ][2], k[KSZ][2], v[KSZ][2];
#pragma unroll
    for (int i = 0; i < KSZ; ++i) {
        const bf16* rp = qkv + rowbase + (size_t)i * N3;
        u32 uq = *reinterpret_cast<const u32*>(rp + coff);
        u32 uk = *reinterpret_cast<const u32*>(rp + 1024 + coff);
        u32 uv = *reinterpret_cast<const u32*>(rp + 2048 + coff);
        q[i][0] = bflo(uq); q[i][1] = bfhi(uq);
        k[i][0] = bflo(uk); k[i][1] = bfhi(uk);
        v[i][0] = bflo(uv); v[i][1] = bfhi(uv);
    }

    float dots[KSZ][KSZ];
#pragma unroll
    for (int i = 0; i < KSZ; ++i)
#pragma unroll
        for (int j = 0; j < KSZ; ++j) {
            float p = q[i][0] * k[j][0] + q[i][1] * k[j][1];
#pragma unroll
            for (int off = 32; off >= 1; off >>= 1)
                p += __shfl_xor(p, off);
            dots[i][j] = p * 0.03125f;   // * C^-0.5
        }

#pragma unroll
    for (int i = 0; i < KSZ; ++i) {
        float m = fmaxf(fmaxf(dots[i][0], dots[i][1]), fmaxf(dots[i][2], dots[i][3]));
        float e[KSZ], s = 0.f;
#pragma unroll
        for (int j = 0; j < KSZ; ++j) { e[j] = __expf(dots[i][j] - m); s += e[j]; }
        float inv = 1.f / s;
        float o0 = 0.f, o1 = 0.f;
#pragma unroll
        for (int j = 0; j < KSZ; ++j) {
            float a = e[j] * inv;
            o0 += a * v[j][0];
            o1 += a * v[j][1];
        }
        size_t orow = (size_t)(b * NW + n) * KSZ + i;
        u32 pk = (u32)f2bf(o0) | ((u32)f2bf(o1) << 16);
        *reinterpret_cast<u32*>(ob + orow * CC + coff) = pk;
    }
}

// ---------------- gather: out[b][l][:] = sum of 1-2 contributing y rows ----------------
__global__ __launch_bounds__(256) void gather_k(const bf16* __restrict__ yb,
                                                float* __restrict__ out)
{
    size_t i = (size_t)blockIdx.x * 256 + threadIdx.x;   // over B*L*C/2 pairs
    size_t e0 = i * 2;
    int col = (int)(e0 & (CC - 1));
    size_t row = e0 >> 10;          // b*L + l
    int l = (int)(row & (LL - 1));
    int b = (int)(row >> 11);

    float s0 = 0.f, s1 = 0.f;
    int n1 = l >> 1, q1 = l & 1;
    if (n1 <= NW - 1) {
        size_t r = (size_t)(b * NW + n1) * KSZ + q1;
        u32 u = *reinterpret_cast<const u32*>(yb + r * CC + col);
        s0 += bflo(u); s1 += bfhi(u);
    }
    int n0v = n1 - 1, q0 = (l & 1) + 2;
    if (n0v >= 0) {
        size_t r = (size_t)(b * NW + n0v) * KSZ + q0;
        u32 u = *reinterpret_cast<const u32*>(yb + r * CC + col);
        s0 += bflo(u); s1 += bfhi(u);
    }
    float2 o; o.x = s0; o.y = s1;
    *reinterpret_cast<float2*>(out + e0) = o;
}

// ---------------- launch ----------------
extern "C" void kernel_launch(void* const* d_in, const int* in_sizes, int n_in,
                              void* d_out, int out_size, void* d_ws, size_t ws_size,
                              hipStream_t stream)
{
    const float* x     = (const float*)d_in[0];
    const float* w_qkv = (const float*)d_in[1];
    const float* w_out = (const float*)d_in[2];
    const float* b_out = (const float*)d_in[3];
    float* out = (float*)d_out;
    char* ws = (char*)d_ws;

    // ws layout (bytes):
    bf16* xb    = (bf16*)(ws);                  // 16384*1024*2  = 33,554,432
    bf16* wqkvT = (bf16*)(ws + 33554432);       //  3072*1024*2  =  6,291,456
    bf16* woutT = (bf16*)(ws + 39845888);       //  1024*1024*2  =  2,097,152
    bf16* qkvb  = (bf16*)(ws + 41943040);       // 16384*3072*2  = 100,663,296
    bf16* yb    = (bf16*)(ws + 41943040);       // aliases qkvb (dead after attn): 32768*1024*2
    bf16* ob    = (bf16*)(ws + 142606336);      // 32768*1024*2  = 67,108,864  (rows padded to 32768)
    // total: 209,715,200 bytes

    cast_x_k<<<2048, 256, 0, stream>>>(x, xb, M1 * CC / 4);
    transpose_cast_k<<<dim3(N3 / 32, CC / 32), 256, 0, stream>>>(w_qkv, wqkvT, CC, N3);
    transpose_cast_k<<<dim3(CC / 32, CC / 32), 256, 0, stream>>>(w_out, woutT, CC, CC);

    // GEMM1: 16384x3072x1024 = 768 tiles -> 256 persistent blocks x 3 tiles
    gemm8p_k<0, 3><<<256, 512, 0, stream>>>(xb, wqkvT, qkvb, nullptr, N3);

    attn_k<<<BB * NW * HEADS / 4, 256, 0, stream>>>(qkvb, ob);

    // GEMM2: 32768x1024x1024 = 512 tiles -> 256 persistent blocks x 2 tiles
    gemm8p_k<1, 2><<<256, 512, 0, stream>>>(ob, woutT, yb, b_out, CC);

    gather_k<<<(BB * LL * CC / 2) / 256, 256, 0, stream>>>(yb, out);
}